// Round 1
// baseline (2306.695 us; speedup 1.0000x reference)
//
#include <hip/hip_runtime.h>
#include <cmath>

#define IMG_H 256
#define IMG_W 256
#define N_B   16
#define N_C   32
#define KS    21
#define HALO  10
#define TX    64
#define TY    16
#define LROWS (TY + 2*HALO)   // 36
#define LCOLS (TX + 2*HALO)   // 84
#define LPITCH 88             // padded LDS pitch (floats), 16B-aligned rows

// ---------------------------------------------------------------------------
// Kernel 1: build the 8 (center,surround) normalized 21x21 kernels into ws,
// and init per-channel min/max bit-arrays.
// wtab layout: [theta][ky*21+kx][2] floats (interleaved wc,ws -> one 8B uniform load)
// ---------------------------------------------------------------------------
__global__ void prep_kernel(float* __restrict__ wtab,
                            unsigned* __restrict__ mnb, unsigned* __restrict__ mxb) {
    int t = blockIdx.x;      // theta index 0..7
    int i = threadIdx.x;     // 0..511
    __shared__ float red0[512];
    __shared__ float red1[512];
    float wc = 0.f, wsv = 0.f;
    if (i < 441) {
        int ky = i / 21, kx = i % 21;
        float theta = (float)((double)t * 3.14159265358979323846 / 8.0);
        float ct = cosf(theta), st = sinf(theta);
        float xi = (float)(ky - 10), yj = (float)(kx - 10);   // meshgrid 'ij'
        float xr =  xi*ct + yj*st;
        float yr = -xi*st + yj*ct;
        const float sx  = 3.65f,      sy  = 3.65f/8.0f;
        const float sx3 = 3.65f*3.0f, sy3 = (3.65f/8.0f)*3.0f;
        wc  = expf(-0.5f*(xr*xr/(sx*sx)   + yr*yr/(sy*sy)));
        wsv = expf(-0.5f*(xr*xr/(sx3*sx3) + yr*yr/(sy3*sy3)));
    }
    red0[i] = wc; red1[i] = wsv;
    __syncthreads();
    for (int s = 256; s > 0; s >>= 1) {
        if (i < s) { red0[i] += red0[i+s]; red1[i] += red1[i+s]; }
        __syncthreads();
    }
    if (i < 441) {
        wtab[(t*441 + i)*2 + 0] = wc  / red0[0];
        wtab[(t*441 + i)*2 + 1] = wsv / red1[0];
    }
    if (t == 0 && i < N_C) { mnb[i] = 0x7f800000u; mxb[i] = 0u; }  // +inf / 0
}

// ---------------------------------------------------------------------------
// Kernel 2: per-channel global min/max of lstd = sqrt(max(E[x^2]-E[x]^2,1e-6))
// over a 3x3 count_include_pad average pool. One block per image row per plane.
// Positive floats -> int-ordered atomics are exact.
// ---------------------------------------------------------------------------
__global__ __launch_bounds__(256) void lstd_minmax_kernel(
    const float* __restrict__ x, unsigned* __restrict__ mnb, unsigned* __restrict__ mxb) {
    int y     = blockIdx.x;          // 0..255
    int plane = blockIdx.y;          // 0..511  (b*32+c)
    int c     = plane & (N_C - 1);
    const float* __restrict__ img = x + (size_t)plane * (IMG_H*IMG_W);
    int xc = threadIdx.x;            // column 0..255
    float s1 = 0.f, s2 = 0.f;
    #pragma unroll
    for (int dy = -1; dy <= 1; ++dy) {
        int yy = y + dy;
        if (0 <= yy && yy < IMG_H) {
            const float* row = img + yy*IMG_W;
            #pragma unroll
            for (int dx = -1; dx <= 1; ++dx) {
                int xx = xc + dx;
                if (0 <= xx && xx < IMG_W) { float v = row[xx]; s1 += v; s2 += v*v; }
            }
        }
    }
    float avg = s1 / 9.0f, avq = s2 / 9.0f;
    float l = sqrtf(fmaxf(avq - avg*avg, 1e-6f));
    float lmin = l, lmax = l;
    for (int off = 32; off >= 1; off >>= 1) {
        lmin = fminf(lmin, __shfl_xor(lmin, off));
        lmax = fmaxf(lmax, __shfl_xor(lmax, off));
    }
    __shared__ float smin[4], smax[4];
    int lane = threadIdx.x & 63, wid = threadIdx.x >> 6;
    if (lane == 0) { smin[wid] = lmin; smax[wid] = lmax; }
    __syncthreads();
    if (threadIdx.x == 0) {
        float m0 = fminf(fminf(smin[0], smin[1]), fminf(smin[2], smin[3]));
        float m1 = fmaxf(fmaxf(smax[0], smax[1]), fmaxf(smax[2], smax[3]));
        atomicMin((int*)&mnb[c], __float_as_int(m0));
        atomicMax((int*)&mxb[c], __float_as_int(m1));
    }
}

// ---------------------------------------------------------------------------
// Kernel 3: main fused kernel.  64x16 output tile per 256-thread block,
// 4 x-consecutive outputs per thread (aligned float4 LDS window).
// Uses exact 180-degree point symmetry of the Gaussians:
//   w[ky][kx] == w[20-ky][20-kx]  ->  1 add + 2 fma per tap-pair (vs 4 fma).
// Weights are wave-uniform global loads (scalar path), keeping LDS for image.
// ---------------------------------------------------------------------------
__global__ __launch_bounds__(256) void texsup_kernel(
    const float* __restrict__ x, const float* __restrict__ wtab,
    const unsigned* __restrict__ mnb, const unsigned* __restrict__ mxb,
    float* __restrict__ out)
{
    __shared__ float tile[LROWS][LPITCH];
    const int plane = blockIdx.z;          // 0..511
    const int b = plane >> 5, c = plane & 31;
    const float* __restrict__ img = x + (size_t)plane * (IMG_H*IMG_W);
    const int tx0 = blockIdx.x * TX, ty0 = blockIdx.y * TY;
    const int tid = threadIdx.x;

    // stage tile (+10 halo each side), zeros outside the image (SAME padding)
    for (int li = tid; li < LROWS*LCOLS; li += 256) {
        int r = li / LCOLS, col = li - r*LCOLS;
        int gy = ty0 - HALO + r, gx = tx0 - HALO + col;
        float v = 0.f;
        if ((unsigned)gy < IMG_H && (unsigned)gx < IMG_W) v = img[gy*IMG_W + gx];
        tile[r][col] = v;
    }
    __syncthreads();

    const float* __restrict__ wt = wtab + (size_t)(b & 7) * (441*2);
    const int tx = tid & 15, ty = tid >> 4;   // 16 x-groups, 16 rows
    const int ox = tx * 4;                    // output col offset inside tile

    float accC[4] = {0.f,0.f,0.f,0.f};
    float accS[4] = {0.f,0.f,0.f,0.f};

    // symmetric row pairs (ky, 20-ky), ky = 0..9
    #pragma unroll 1
    for (int kyp = 0; kyp < 10; ++kyp) {
        float vA[24], vB[24];
        const float* rA = &tile[ty + kyp][ox];
        const float* rB = &tile[ty + 20 - kyp][ox];
        #pragma unroll
        for (int q = 0; q < 6; ++q) {
            float4 a4 = *(const float4*)(rA + 4*q);
            float4 b4 = *(const float4*)(rB + 4*q);
            vA[4*q+0]=a4.x; vA[4*q+1]=a4.y; vA[4*q+2]=a4.z; vA[4*q+3]=a4.w;
            vB[4*q+0]=b4.x; vB[4*q+1]=b4.y; vB[4*q+2]=b4.z; vB[4*q+3]=b4.w;
        }
        #pragma unroll
        for (int kx = 0; kx < 21; ++kx) {
            const float wc = wt[(kyp*21 + kx)*2 + 0];
            const float ws = wt[(kyp*21 + kx)*2 + 1];
            #pragma unroll
            for (int o = 0; o < 4; ++o) {
                float s = vA[kx + o] + vB[20 - kx + o];   // pair (ky,kx)+(20-ky,20-kx)
                accC[o] = fmaf(wc, s, accC[o]);
                accS[o] = fmaf(ws, s, accS[o]);
            }
        }
    }
    // middle row ky = 10: pair (10,kx)+(10,20-kx), plus lone center tap
    {
        float vM[24];
        const float* rM = &tile[ty + 10][ox];
        #pragma unroll
        for (int q = 0; q < 6; ++q) {
            float4 m4 = *(const float4*)(rM + 4*q);
            vM[4*q+0]=m4.x; vM[4*q+1]=m4.y; vM[4*q+2]=m4.z; vM[4*q+3]=m4.w;
        }
        #pragma unroll
        for (int kx = 0; kx < 10; ++kx) {
            const float wc = wt[(210 + kx)*2 + 0];
            const float ws = wt[(210 + kx)*2 + 1];
            #pragma unroll
            for (int o = 0; o < 4; ++o) {
                float s = vM[kx + o] + vM[20 - kx + o];
                accC[o] = fmaf(wc, s, accC[o]);
                accS[o] = fmaf(ws, s, accS[o]);
            }
        }
        const float wc = wt[220*2 + 0];
        const float ws = wt[220*2 + 1];
        #pragma unroll
        for (int o = 0; o < 4; ++o) {
            float v = vM[10 + o];
            accC[o] = fmaf(wc, v, accC[o]);
            accS[o] = fmaf(ws, v, accS[o]);
        }
    }

    // epilogue: recompute local std from the LDS tile (zeros outside image match
    // count_include_pad), normalize with per-channel min/max, combine, ReLU.
    const float mnv = __uint_as_float(mnb[c]);
    const float mxv = __uint_as_float(mxb[c]);
    const float inv = 1.0f / (mxv - mnv + 1e-8f);
    float res[4];
    #pragma unroll
    for (int o = 0; o < 4; ++o) {
        float s1 = 0.f, s2 = 0.f;
        #pragma unroll
        for (int dy = -1; dy <= 1; ++dy) {
            #pragma unroll
            for (int dx = -1; dx <= 1; ++dx) {
                float v = tile[ty + 10 + dy][ox + o + 10 + dx];
                s1 += v; s2 += v*v;
            }
        }
        float avg = s1 / 9.0f, avq = s2 / 9.0f;
        float l = sqrtf(fmaxf(avq - avg*avg, 1e-6f));
        l = (l - mnv) * inv;
        res[o] = fmaxf(accC[o] - l * accS[o], 0.0f);
    }
    *(float4*)(out + (size_t)plane*(IMG_H*IMG_W) + (size_t)(ty0+ty)*IMG_W + tx0 + ox) =
        make_float4(res[0], res[1], res[2], res[3]);
}

// ---------------------------------------------------------------------------
extern "C" void kernel_launch(void* const* d_in, const int* in_sizes, int n_in,
                              void* d_out, int out_size, void* d_ws, size_t ws_size,
                              hipStream_t stream) {
    const float* x = (const float*)d_in[0];
    float* out = (float*)d_out;

    float*    wtab = (float*)d_ws;                                   // 8*441*2 f32 = 28224 B
    unsigned* mnb  = (unsigned*)((char*)d_ws + 8*441*2*sizeof(float));
    unsigned* mxb  = mnb + N_C;

    hipLaunchKernelGGL(prep_kernel, dim3(8), dim3(512), 0, stream, wtab, mnb, mxb);
    hipLaunchKernelGGL(lstd_minmax_kernel, dim3(IMG_H, N_B*N_C), dim3(256), 0, stream,
                       x, mnb, mxb);
    hipLaunchKernelGGL(texsup_kernel, dim3(IMG_W/TX, IMG_H/TY, N_B*N_C), dim3(256), 0, stream,
                       x, wtab, mnb, mxb, out);
}

// Round 2
// 1379.999 us; speedup vs baseline: 1.6715x; 1.6715x over previous
//
#include <hip/hip_runtime.h>
#include <cmath>

#define IMG_H 256
#define IMG_W 256
#define N_B   16
#define N_C   32
#define HALO  10
#define TY    32                 // output rows per block
#define LROWS (TY + 2*HALO)      // 52
#define LPITCH 276               // 10 + 256 + 10 floats; 1104B rows (16B-aligned)

// ---------------------------------------------------------------------------
// Kernel 1: build the 8 (center,surround) normalized 21x21 kernels into ws,
// init per-channel min/max bit-arrays.
// wtab layout: [theta][ky*21+kx][2] floats (wc,ws interleaved -> uniform s_load)
// ---------------------------------------------------------------------------
__global__ void prep_kernel(float* __restrict__ wtab,
                            unsigned* __restrict__ mnb, unsigned* __restrict__ mxb) {
    int t = blockIdx.x;      // theta index 0..7
    int i = threadIdx.x;     // 0..511
    __shared__ float red0[512];
    __shared__ float red1[512];
    float wc = 0.f, wsv = 0.f;
    if (i < 441) {
        int ky = i / 21, kx = i % 21;
        float theta = (float)((double)t * 3.14159265358979323846 / 8.0);
        float ct = cosf(theta), st = sinf(theta);
        float xi = (float)(ky - 10), yj = (float)(kx - 10);   // meshgrid 'ij'
        float xr =  xi*ct + yj*st;
        float yr = -xi*st + yj*ct;
        const float sx  = 3.65f,      sy  = 3.65f/8.0f;
        const float sx3 = 3.65f*3.0f, sy3 = (3.65f/8.0f)*3.0f;
        wc  = expf(-0.5f*(xr*xr/(sx*sx)   + yr*yr/(sy*sy)));
        wsv = expf(-0.5f*(xr*xr/(sx3*sx3) + yr*yr/(sy3*sy3)));
    }
    red0[i] = wc; red1[i] = wsv;
    __syncthreads();
    for (int s = 256; s > 0; s >>= 1) {
        if (i < s) { red0[i] += red0[i+s]; red1[i] += red1[i+s]; }
        __syncthreads();
    }
    if (i < 441) {
        wtab[(t*441 + i)*2 + 0] = wc  / red0[0];
        wtab[(t*441 + i)*2 + 1] = wsv / red1[0];
    }
    if (t == 0 && i < N_C) { mnb[i] = 0x7f800000u; mxb[i] = 0u; }  // +inf / 0
}

// ---------------------------------------------------------------------------
// Kernel 2: per-channel global min/max of lstd (3x3 count_include_pad pool).
// Block = 4 rows of one plane; thread = 4 consecutive pixels (float4 loads).
// Column-sum trick: 6 col sums -> 4 outputs. Positive floats -> int atomics.
// ---------------------------------------------------------------------------
__global__ __launch_bounds__(256) void lstd_minmax_kernel(
    const float* __restrict__ x, unsigned* __restrict__ mnb, unsigned* __restrict__ mxb) {
    const int plane = blockIdx.y;                 // 0..511
    const int c     = plane & (N_C - 1);
    const float* __restrict__ img = x + (size_t)plane * (IMG_H*IMG_W);
    const int y  = blockIdx.x * 4 + (threadIdx.x >> 6);   // row
    const int l  = threadIdx.x & 63;
    const int cx = l * 4;                          // first output col

    float c1[6] = {0,0,0,0,0,0};
    float c2[6] = {0,0,0,0,0,0};
    #pragma unroll
    for (int dy = -1; dy <= 1; ++dy) {
        int yy = y + dy;
        if ((unsigned)yy < IMG_H) {
            const float* row = img + yy*IMG_W;
            float4 m = *(const float4*)(row + cx);
            float lf = (cx > 0)       ? row[cx-1] : 0.f;
            float rt = (cx+4 < IMG_W) ? row[cx+4] : 0.f;
            float v[6] = {lf, m.x, m.y, m.z, m.w, rt};
            #pragma unroll
            for (int j = 0; j < 6; ++j) { c1[j] += v[j]; c2[j] += v[j]*v[j]; }
        }
    }
    float lmin = 1e30f, lmax = -1e30f;
    #pragma unroll
    for (int o = 0; o < 4; ++o) {
        float s1 = c1[o] + c1[o+1] + c1[o+2];
        float s2 = c2[o] + c2[o+1] + c2[o+2];
        float avg = s1 * (1.0f/9.0f), avq = s2 * (1.0f/9.0f);
        float lv = sqrtf(fmaxf(avq - avg*avg, 1e-6f));
        lmin = fminf(lmin, lv); lmax = fmaxf(lmax, lv);
    }
    #pragma unroll
    for (int off = 32; off >= 1; off >>= 1) {
        lmin = fminf(lmin, __shfl_xor(lmin, off));
        lmax = fmaxf(lmax, __shfl_xor(lmax, off));
    }
    __shared__ float smin[4], smax[4];
    int wid = threadIdx.x >> 6;
    if (l == 0) { smin[wid] = lmin; smax[wid] = lmax; }
    __syncthreads();
    if (threadIdx.x == 0) {
        float m0 = fminf(fminf(smin[0], smin[1]), fminf(smin[2], smin[3]));
        float m1 = fmaxf(fmaxf(smax[0], smax[1]), fmaxf(smax[2], smax[3]));
        atomicMin((int*)&mnb[c], __float_as_int(m0));
        atomicMax((int*)&mxb[c], __float_as_int(m1));
    }
}

// ---------------------------------------------------------------------------
// Kernel 3: main fused conv kernel.
// 512 threads = 8 waves; one wave covers a FULL 256-wide output row
// (64 lanes x 4 cols) -> every LDS float4 read is a contiguous 1024B wave
// access: conflict-free by construction. Each wave does 4 rows sequentially.
// 180-degree point symmetry: w[ky][kx]==w[20-ky][20-kx] -> 1 add + 2 fma.
// __launch_bounds__(512,4): 128-VGPR cap keeps the 12 float4/pair in regs,
// 2 blocks/CU (57.4KB LDS) = 16 waves/CU.
// ---------------------------------------------------------------------------
__global__ __launch_bounds__(512, 4) void texsup_kernel(
    const float* __restrict__ x, const float* __restrict__ wtab,
    const unsigned* __restrict__ mnb, const unsigned* __restrict__ mxb,
    float* __restrict__ out)
{
    __shared__ float tile[LROWS][LPITCH];
    const int plane = blockIdx.z;          // 0..511
    const int b = plane >> 5, c = plane & 31;
    const float* __restrict__ img = x + (size_t)plane * (IMG_H*IMG_W);
    const int by0 = blockIdx.y * TY;
    const int tid = threadIdx.x;
    const int wid = tid >> 6, lane = tid & 63;
    const int ox = lane * 4;               // tile col of first output (== img col offset by -10.. see below)

    // stage: tile row r <-> img row by0 + r - 10; tile col c <-> img col c - 10
    for (int r = wid; r < LROWS; r += 8) {
        int gy = by0 + r - HALO;
        float4 v = make_float4(0.f, 0.f, 0.f, 0.f);
        if ((unsigned)gy < IMG_H) v = *(const float4*)(img + gy*IMG_W + ox);
        *(float4*)&tile[r][HALO + ox] = v;
        if (lane < 10)       tile[r][lane]       = 0.f;    // cols 0..9
        else if (lane < 20)  tile[r][lane + 256] = 0.f;    // cols 266..275
    }
    __syncthreads();

    const float* __restrict__ wt = wtab + (size_t)(b & 7) * (441*2);
    const float mnv = __uint_as_float(mnb[c]);
    const float mxv = __uint_as_float(mxb[c]);
    const float inv = 1.0f / (mxv - mnv + 1e-8f);

    #pragma unroll 1
    for (int rr = 0; rr < 4; ++rr) {
        const int wy = wid * 4 + rr;       // output row within tile (0..31)

        float accC[4] = {0.f,0.f,0.f,0.f};
        float accS[4] = {0.f,0.f,0.f,0.f};

        // symmetric row pairs (ky, 20-ky), ky = 0..9. Output col lane*4+o needs
        // tile cols lane*4 + kx + o  (kx 0..20, o 0..3) -> window [ox, ox+23].
        #pragma unroll 1
        for (int kyp = 0; kyp < 10; ++kyp) {
            const float* rA = &tile[wy + kyp][ox];
            const float* rB = &tile[wy + 20 - kyp][ox];
            float vA[24], vB[24];
            #pragma unroll
            for (int q = 0; q < 6; ++q) {
                float4 a4 = *(const float4*)(rA + 4*q);
                float4 b4 = *(const float4*)(rB + 4*q);
                vA[4*q+0]=a4.x; vA[4*q+1]=a4.y; vA[4*q+2]=a4.z; vA[4*q+3]=a4.w;
                vB[4*q+0]=b4.x; vB[4*q+1]=b4.y; vB[4*q+2]=b4.z; vB[4*q+3]=b4.w;
            }
            const float* w = wt + kyp*42;
            #pragma unroll
            for (int kx = 0; kx < 21; ++kx) {
                const float wc = w[kx*2 + 0];
                const float ws = w[kx*2 + 1];
                #pragma unroll
                for (int o = 0; o < 4; ++o) {
                    float s = vA[kx + o] + vB[20 - kx + o];
                    accC[o] = fmaf(wc, s, accC[o]);
                    accS[o] = fmaf(ws, s, accS[o]);
                }
            }
        }
        // middle row ky = 10
        {
            const float* rM = &tile[wy + 10][ox];
            float vM[24];
            #pragma unroll
            for (int q = 0; q < 6; ++q) {
                float4 m4 = *(const float4*)(rM + 4*q);
                vM[4*q+0]=m4.x; vM[4*q+1]=m4.y; vM[4*q+2]=m4.z; vM[4*q+3]=m4.w;
            }
            const float* w = wt + 210*2;
            #pragma unroll
            for (int kx = 0; kx < 10; ++kx) {
                const float wc = w[kx*2 + 0];
                const float ws = w[kx*2 + 1];
                #pragma unroll
                for (int o = 0; o < 4; ++o) {
                    float s = vM[kx + o] + vM[20 - kx + o];
                    accC[o] = fmaf(wc, s, accC[o]);
                    accS[o] = fmaf(ws, s, accS[o]);
                }
            }
            const float wc = wt[220*2 + 0];
            const float ws = wt[220*2 + 1];
            #pragma unroll
            for (int o = 0; o < 4; ++o) {
                float v = vM[10 + o];
                accC[o] = fmaf(wc, v, accC[o]);
                accS[o] = fmaf(ws, v, accS[o]);
            }
        }

        // epilogue: local std from tile (zeros outside image == count_include_pad).
        // window cols ox + o+10+dx (dx -1..1) -> tile cols [ox+9, ox+14] -> two
        // aligned float4 loads per row at ox+8 / ox+12 (contiguous wave access).
        float d1[6] = {0,0,0,0,0,0};
        float d2[6] = {0,0,0,0,0,0};
        #pragma unroll
        for (int dy = -1; dy <= 1; ++dy) {
            const float* rw = &tile[wy + 10 + dy][ox + 8];
            float4 u0 = *(const float4*)(rw);
            float4 u1 = *(const float4*)(rw + 4);
            float v[6] = {u0.y, u0.z, u0.w, u1.x, u1.y, u1.z};  // cols ox+9..ox+14
            #pragma unroll
            for (int j = 0; j < 6; ++j) { d1[j] += v[j]; d2[j] += v[j]*v[j]; }
        }
        float res[4];
        #pragma unroll
        for (int o = 0; o < 4; ++o) {
            float s1 = d1[o] + d1[o+1] + d1[o+2];
            float s2 = d2[o] + d2[o+1] + d2[o+2];
            float avg = s1 * (1.0f/9.0f), avq = s2 * (1.0f/9.0f);
            float lv = sqrtf(fmaxf(avq - avg*avg, 1e-6f));
            lv = (lv - mnv) * inv;
            res[o] = fmaxf(accC[o] - lv * accS[o], 0.0f);
        }
        *(float4*)(out + (size_t)plane*(IMG_H*IMG_W) + (size_t)(by0+wy)*IMG_W + ox) =
            make_float4(res[0], res[1], res[2], res[3]);
    }
}

// ---------------------------------------------------------------------------
extern "C" void kernel_launch(void* const* d_in, const int* in_sizes, int n_in,
                              void* d_out, int out_size, void* d_ws, size_t ws_size,
                              hipStream_t stream) {
    const float* x = (const float*)d_in[0];
    float* out = (float*)d_out;

    float*    wtab = (float*)d_ws;                                   // 8*441*2 f32 = 28224 B
    unsigned* mnb  = (unsigned*)((char*)d_ws + 8*441*2*sizeof(float));
    unsigned* mxb  = mnb + N_C;

    hipLaunchKernelGGL(prep_kernel, dim3(8), dim3(512), 0, stream, wtab, mnb, mxb);
    hipLaunchKernelGGL(lstd_minmax_kernel, dim3(IMG_H/4, N_B*N_C), dim3(256), 0, stream,
                       x, mnb, mxb);
    hipLaunchKernelGGL(texsup_kernel, dim3(1, IMG_H/TY, N_B*N_C), dim3(512), 0, stream,
                       x, wtab, mnb, mxb, out);
}

// Round 3
// 887.360 us; speedup vs baseline: 2.5995x; 1.5552x over previous
//
#include <hip/hip_runtime.h>
#include <cmath>

#define IMG_H 256
#define IMG_W 256
#define N_B   16
#define N_C   32
#define HALO  10
#define TY    32                 // output rows per block
#define LROWS (TY + 2*HALO)      // 52
#define LPITCH 276               // 10 + 256 + 10 floats

typedef float f32x4 __attribute__((ext_vector_type(4)));
typedef float f32x2 __attribute__((ext_vector_type(2)));

// element i (0..23) of a 6-vector f32x4 window
#define EL(arr, i) arr[(i) >> 2][(i) & 3]

// ---------------------------------------------------------------------------
// Kernel 1: build the 8 (center,surround) normalized 21x21 kernels into ws,
// init per-channel min/max bit-arrays.
// wtab layout: [theta][ky*21+kx][2] floats (wc,ws interleaved)
// ---------------------------------------------------------------------------
__global__ void prep_kernel(float* __restrict__ wtab,
                            unsigned* __restrict__ mnb, unsigned* __restrict__ mxb) {
    int t = blockIdx.x;      // theta index 0..7
    int i = threadIdx.x;     // 0..511
    __shared__ float red0[512];
    __shared__ float red1[512];
    float wc = 0.f, wsv = 0.f;
    if (i < 441) {
        int ky = i / 21, kx = i % 21;
        float theta = (float)((double)t * 3.14159265358979323846 / 8.0);
        float ct = cosf(theta), st = sinf(theta);
        float xi = (float)(ky - 10), yj = (float)(kx - 10);   // meshgrid 'ij'
        float xr =  xi*ct + yj*st;
        float yr = -xi*st + yj*ct;
        const float sx  = 3.65f,      sy  = 3.65f/8.0f;
        const float sx3 = 3.65f*3.0f, sy3 = (3.65f/8.0f)*3.0f;
        wc  = expf(-0.5f*(xr*xr/(sx*sx)   + yr*yr/(sy*sy)));
        wsv = expf(-0.5f*(xr*xr/(sx3*sx3) + yr*yr/(sy3*sy3)));
    }
    red0[i] = wc; red1[i] = wsv;
    __syncthreads();
    for (int s = 256; s > 0; s >>= 1) {
        if (i < s) { red0[i] += red0[i+s]; red1[i] += red1[i+s]; }
        __syncthreads();
    }
    if (i < 441) {
        wtab[(t*441 + i)*2 + 0] = wc  / red0[0];
        wtab[(t*441 + i)*2 + 1] = wsv / red1[0];
    }
    if (t == 0 && i < N_C) { mnb[i] = 0x7f800000u; mxb[i] = 0u; }  // +inf / 0
}

// ---------------------------------------------------------------------------
// Kernel 2: per-channel global min/max of lstd (3x3 count_include_pad pool).
// One wave = one image row (64 lanes x 4 px, float4 loads); neighbor columns
// come from adjacent lanes via __shfl (no scalar edge loads).
// ---------------------------------------------------------------------------
__global__ __launch_bounds__(256) void lstd_minmax_kernel(
    const float* __restrict__ x, unsigned* __restrict__ mnb, unsigned* __restrict__ mxb) {
    const int plane = blockIdx.y;                 // 0..511
    const int c     = plane & (N_C - 1);
    const float* __restrict__ img = x + (size_t)plane * (IMG_H*IMG_W);
    const int y  = blockIdx.x * 4 + (threadIdx.x >> 6);   // output row
    const int l  = threadIdx.x & 63;
    const int cx = l * 4;

    float c1[6] = {0,0,0,0,0,0};
    float c2[6] = {0,0,0,0,0,0};
    #pragma unroll
    for (int dy = -1; dy <= 1; ++dy) {
        int yy = y + dy;
        if ((unsigned)yy < IMG_H) {
            f32x4 m = *(const f32x4*)(img + yy*IMG_W + cx);
            float lf = __shfl_up(m[3], 1);   // lane l-1's m.w == row[cx-1]
            float rt = __shfl_down(m[0], 1); // lane l+1's m.x == row[cx+4]
            if (l == 0)  lf = 0.f;           // cx==0: zero pad
            if (l == 63) rt = 0.f;           // cx+4==256: zero pad
            float v[6] = {lf, m[0], m[1], m[2], m[3], rt};
            #pragma unroll
            for (int j = 0; j < 6; ++j) { c1[j] += v[j]; c2[j] += v[j]*v[j]; }
        }
    }
    float lmin = 1e30f, lmax = -1e30f;
    #pragma unroll
    for (int o = 0; o < 4; ++o) {
        float s1 = c1[o] + c1[o+1] + c1[o+2];
        float s2 = c2[o] + c2[o+1] + c2[o+2];
        float avg = s1 * (1.0f/9.0f), avq = s2 * (1.0f/9.0f);
        float lv = sqrtf(fmaxf(avq - avg*avg, 1e-6f));
        lmin = fminf(lmin, lv); lmax = fmaxf(lmax, lv);
    }
    #pragma unroll
    for (int off = 32; off >= 1; off >>= 1) {
        lmin = fminf(lmin, __shfl_xor(lmin, off));
        lmax = fmaxf(lmax, __shfl_xor(lmax, off));
    }
    __shared__ float smin[4], smax[4];
    int wid = threadIdx.x >> 6;
    if (l == 0) { smin[wid] = lmin; smax[wid] = lmax; }
    __syncthreads();
    if (threadIdx.x == 0) {
        float m0 = fminf(fminf(smin[0], smin[1]), fminf(smin[2], smin[3]));
        float m1 = fmaxf(fmaxf(smax[0], smax[1]), fmaxf(smax[2], smax[3]));
        atomicMin((int*)&mnb[c], __float_as_int(m0));
        atomicMax((int*)&mxb[c], __float_as_int(m1));
    }
}

// ---------------------------------------------------------------------------
// Kernel 3: main fused conv kernel.
// One wave covers a full 256-wide output row (64 lanes x 4 cols): every LDS
// access is a contiguous 1024B wave ds_read_b128 (conflict-free).
// The 24-float sliding windows are loaded as f32x4 and passed through an
// empty asm ("+v") so the compiler CANNOT refold them into per-element
// ds_read_b32 (the round-2 failure: 8-way bank conflicts, 3.6e8 cycles).
// 180-degree point symmetry: w[ky][kx]==w[20-ky][20-kx] -> 1 add + 2 fma
// per tap-pair. f32x2 math to allow v_pk_* packing.
// ---------------------------------------------------------------------------
__global__ __launch_bounds__(512, 4) void texsup_kernel(
    const float* __restrict__ x, const float* __restrict__ wtab,
    const unsigned* __restrict__ mnb, const unsigned* __restrict__ mxb,
    float* __restrict__ out)
{
    __shared__ float tile[LROWS][LPITCH];
    const int plane = blockIdx.z;          // 0..511
    const int b = plane >> 5, c = plane & 31;
    const float* __restrict__ img = x + (size_t)plane * (IMG_H*IMG_W);
    const int by0 = blockIdx.y * TY;
    const int tid = threadIdx.x;
    const int wid = tid >> 6, lane = tid & 63;
    const int ox = lane * 4;

    // stage: tile row r <-> img row by0 + r - 10; tile col t <-> img col t - 10
    for (int r = wid; r < LROWS; r += 8) {
        int gy = by0 + r - HALO;
        f32x4 v = {0.f, 0.f, 0.f, 0.f};
        if ((unsigned)gy < IMG_H) v = *(const f32x4*)(img + gy*IMG_W + ox);
        *(f32x4*)&tile[r][HALO + ox] = v;
        if (lane < 10)       tile[r][lane]       = 0.f;    // cols 0..9
        else if (lane < 20)  tile[r][lane + 256] = 0.f;    // cols 266..275
    }
    __syncthreads();

    const float* __restrict__ wt = wtab + (size_t)(b & 7) * (441*2);
    const float mnv = __uint_as_float(mnb[c]);
    const float mxv = __uint_as_float(mxb[c]);
    const float inv = 1.0f / (mxv - mnv + 1e-8f);

    #pragma unroll 1
    for (int rr = 0; rr < 4; ++rr) {
        const int wy = wid * 4 + rr;       // output row within tile (0..31)

        f32x2 aC[2] = {{0.f,0.f},{0.f,0.f}};
        f32x2 aS[2] = {{0.f,0.f},{0.f,0.f}};

        // symmetric row pairs (ky, 20-ky), ky = 0..9
        #pragma unroll 1
        for (int kyp = 0; kyp < 10; ++kyp) {
            const float* rA = &tile[wy + kyp][ox];
            const float* rB = &tile[wy + 20 - kyp][ox];
            f32x4 A[6], B[6];
            #pragma unroll
            for (int q = 0; q < 6; ++q) {
                A[q] = *(const f32x4*)(rA + 4*q);
                B[q] = *(const f32x4*)(rB + 4*q);
            }
            #pragma unroll
            for (int q = 0; q < 6; ++q) {
                asm volatile("" : "+v"(A[q]));
                asm volatile("" : "+v"(B[q]));
            }
            const float* w = wt + kyp*42;
            #pragma unroll
            for (int kx = 0; kx < 21; ++kx) {
                const float wc = w[kx*2 + 0];
                const float ws = w[kx*2 + 1];
                const f32x2 w2c = {wc, wc}, w2s = {ws, ws};
                #pragma unroll
                for (int p = 0; p < 2; ++p) {
                    f32x2 s = { EL(A, kx + 2*p)     + EL(B, 20 - kx + 2*p),
                                EL(A, kx + 2*p + 1) + EL(B, 20 - kx + 2*p + 1) };
                    aC[p] = __builtin_elementwise_fma(w2c, s, aC[p]);
                    aS[p] = __builtin_elementwise_fma(w2s, s, aS[p]);
                }
            }
        }
        // middle row ky = 10
        {
            const float* rM = &tile[wy + 10][ox];
            f32x4 M[6];
            #pragma unroll
            for (int q = 0; q < 6; ++q) M[q] = *(const f32x4*)(rM + 4*q);
            #pragma unroll
            for (int q = 0; q < 6; ++q) asm volatile("" : "+v"(M[q]));
            const float* w = wt + 210*2;
            #pragma unroll
            for (int kx = 0; kx < 10; ++kx) {
                const float wc = w[kx*2 + 0];
                const float ws = w[kx*2 + 1];
                const f32x2 w2c = {wc, wc}, w2s = {ws, ws};
                #pragma unroll
                for (int p = 0; p < 2; ++p) {
                    f32x2 s = { EL(M, kx + 2*p)     + EL(M, 20 - kx + 2*p),
                                EL(M, kx + 2*p + 1) + EL(M, 20 - kx + 2*p + 1) };
                    aC[p] = __builtin_elementwise_fma(w2c, s, aC[p]);
                    aS[p] = __builtin_elementwise_fma(w2s, s, aS[p]);
                }
            }
            const float wc = wt[220*2 + 0];
            const float ws = wt[220*2 + 1];
            const f32x2 w2c = {wc, wc}, w2s = {ws, ws};
            #pragma unroll
            for (int p = 0; p < 2; ++p) {
                f32x2 v = { EL(M, 10 + 2*p), EL(M, 11 + 2*p) };
                aC[p] = __builtin_elementwise_fma(w2c, v, aC[p]);
                aS[p] = __builtin_elementwise_fma(w2s, v, aS[p]);
            }
        }

        // epilogue: local std from tile (zeros outside image == count_include_pad)
        float d1[6] = {0,0,0,0,0,0};
        float d2[6] = {0,0,0,0,0,0};
        #pragma unroll
        for (int dy = -1; dy <= 1; ++dy) {
            const float* rw = &tile[wy + 10 + dy][ox + 8];
            f32x4 u0 = *(const f32x4*)(rw);
            f32x4 u1 = *(const f32x4*)(rw + 4);
            float v[6] = {u0[1], u0[2], u0[3], u1[0], u1[1], u1[2]};  // cols ox+9..ox+14
            #pragma unroll
            for (int j = 0; j < 6; ++j) { d1[j] += v[j]; d2[j] += v[j]*v[j]; }
        }
        float res[4];
        #pragma unroll
        for (int o = 0; o < 4; ++o) {
            float s1 = d1[o] + d1[o+1] + d1[o+2];
            float s2 = d2[o] + d2[o+1] + d2[o+2];
            float avg = s1 * (1.0f/9.0f), avq = s2 * (1.0f/9.0f);
            float lv = sqrtf(fmaxf(avq - avg*avg, 1e-6f));
            lv = (lv - mnv) * inv;
            float cc = aC[o>>1][o&1], ss = aS[o>>1][o&1];
            res[o] = fmaxf(cc - lv * ss, 0.0f);
        }
        *(f32x4*)(out + (size_t)plane*(IMG_H*IMG_W) + (size_t)(by0+wy)*IMG_W + ox) =
            (f32x4){res[0], res[1], res[2], res[3]};
    }
}

// ---------------------------------------------------------------------------
extern "C" void kernel_launch(void* const* d_in, const int* in_sizes, int n_in,
                              void* d_out, int out_size, void* d_ws, size_t ws_size,
                              hipStream_t stream) {
    const float* x = (const float*)d_in[0];
    float* out = (float*)d_out;

    float*    wtab = (float*)d_ws;                                   // 8*441*2 f32 = 28224 B
    unsigned* mnb  = (unsigned*)((char*)d_ws + 8*441*2*sizeof(float));
    unsigned* mxb  = mnb + N_C;

    hipLaunchKernelGGL(prep_kernel, dim3(8), dim3(512), 0, stream, wtab, mnb, mxb);
    hipLaunchKernelGGL(lstd_minmax_kernel, dim3(IMG_H/4, N_B*N_C), dim3(256), 0, stream,
                       x, mnb, mxb);
    hipLaunchKernelGGL(texsup_kernel, dim3(1, IMG_H/TY, N_B*N_C), dim3(512), 0, stream,
                       x, wtab, mnb, mxb, out);
}

// Round 4
// 639.417 us; speedup vs baseline: 3.6075x; 1.3878x over previous
//
#include <hip/hip_runtime.h>
#include <cmath>

#define IMG_H 256
#define IMG_W 256
#define N_B   16
#define N_C   32
#define HALO  10
#define TY    32                 // output rows per block
#define LROWS (TY + 2*HALO)      // 52
#define LPITCH 276               // 276 % 32 == 20: consecutive rows land on disjoint bank halves

typedef float f32x4 __attribute__((ext_vector_type(4)));

// element i of a bank of f32x4 quads
#define EL(arr, i) arr[(i) >> 2][(i) & 3]

// ---------------------------------------------------------------------------
// Kernel 1: build the 8 (center,surround) normalized 21x21 kernels,
// init per-channel min/max bit-arrays.
// wtab layout: [theta][ky*21+kx][2] floats (wc,ws interleaved)
// ---------------------------------------------------------------------------
__global__ void prep_kernel(float* __restrict__ wtab,
                            unsigned* __restrict__ mnb, unsigned* __restrict__ mxb) {
    int t = blockIdx.x;      // theta index 0..7
    int i = threadIdx.x;     // 0..511
    __shared__ float red0[512];
    __shared__ float red1[512];
    float wc = 0.f, wsv = 0.f;
    if (i < 441) {
        int ky = i / 21, kx = i % 21;
        float theta = (float)((double)t * 3.14159265358979323846 / 8.0);
        float ct = cosf(theta), st = sinf(theta);
        float xi = (float)(ky - 10), yj = (float)(kx - 10);   // meshgrid 'ij'
        float xr =  xi*ct + yj*st;
        float yr = -xi*st + yj*ct;
        const float sx  = 3.65f,      sy  = 3.65f/8.0f;
        const float sx3 = 3.65f*3.0f, sy3 = (3.65f/8.0f)*3.0f;
        wc  = expf(-0.5f*(xr*xr/(sx*sx)   + yr*yr/(sy*sy)));
        wsv = expf(-0.5f*(xr*xr/(sx3*sx3) + yr*yr/(sy3*sy3)));
    }
    red0[i] = wc; red1[i] = wsv;
    __syncthreads();
    for (int s = 256; s > 0; s >>= 1) {
        if (i < s) { red0[i] += red0[i+s]; red1[i] += red1[i+s]; }
        __syncthreads();
    }
    if (i < 441) {
        wtab[(t*441 + i)*2 + 0] = wc  / red0[0];
        wtab[(t*441 + i)*2 + 1] = wsv / red1[0];
    }
    if (t == 0 && i < N_C) { mnb[i] = 0x7f800000u; mxb[i] = 0u; }  // +inf / 0
}

// ---------------------------------------------------------------------------
// Kernel 2: per-channel global min/max of lstd (3x3 count_include_pad pool).
// Streaming column kernel: thread owns 4 columns x 16 rows with a 3-row
// register ring; each input element loaded ~1.1x (vs 3x before). Neighbors
// from adjacent lanes via __shfl. One atomic pair per block.
// ---------------------------------------------------------------------------
#define LOADROW(yy, V, Q) {                                              \
    f32x4 m = {0.f,0.f,0.f,0.f};                                         \
    if ((unsigned)(yy) < IMG_H) m = *(const f32x4*)(img + (yy)*IMG_W + cx); \
    float lf = __shfl_up(m[3], 1);                                       \
    float rt = __shfl_down(m[0], 1);                                     \
    if (l == 0)  lf = 0.f;                                               \
    if (l == 63) rt = 0.f;                                               \
    V[0]=lf; V[1]=m[0]; V[2]=m[1]; V[3]=m[2]; V[4]=m[3]; V[5]=rt;        \
    Q[0]=lf*lf; Q[1]=m[0]*m[0]; Q[2]=m[1]*m[1];                          \
    Q[3]=m[2]*m[2]; Q[4]=m[3]*m[3]; Q[5]=rt*rt;                          \
}

__global__ __launch_bounds__(256) void lstd_minmax_kernel(
    const float* __restrict__ x, unsigned* __restrict__ mnb, unsigned* __restrict__ mxb) {
    const int plane = blockIdx.y;                 // 0..511
    const int c     = plane & (N_C - 1);
    const float* __restrict__ img = x + (size_t)plane * (IMG_H*IMG_W);
    const int w  = threadIdx.x >> 6, l = threadIdx.x & 63;
    const int y0 = blockIdx.x * 64 + w * 16;      // 16 output rows per thread
    const int cx = l * 4;

    float v[3][6], q[3][6];
    LOADROW(y0-1, v[0], q[0]);
    LOADROW(y0,   v[1], q[1]);

    float lmin = 1e30f, lmax = -1e30f;
    #pragma unroll
    for (int i = 0; i < 16; ++i) {
        LOADROW(y0+i+1, v[(i+2)%3], q[(i+2)%3]);
        const float* a  = v[i%3];  const float* b  = v[(i+1)%3];  const float* e  = v[(i+2)%3];
        const float* qa = q[i%3];  const float* qb = q[(i+1)%3];  const float* qe = q[(i+2)%3];
        float s1[6], s2[6];
        #pragma unroll
        for (int j = 0; j < 6; ++j) { s1[j] = a[j]+b[j]+e[j]; s2[j] = qa[j]+qb[j]+qe[j]; }
        #pragma unroll
        for (int o = 0; o < 4; ++o) {
            float t1 = s1[o] + s1[o+1] + s1[o+2];
            float t2 = s2[o] + s2[o+1] + s2[o+2];
            float avg = t1 * (1.0f/9.0f), avq = t2 * (1.0f/9.0f);
            float lv = sqrtf(fmaxf(avq - avg*avg, 1e-6f));
            lmin = fminf(lmin, lv); lmax = fmaxf(lmax, lv);
        }
    }
    #pragma unroll
    for (int off = 32; off >= 1; off >>= 1) {
        lmin = fminf(lmin, __shfl_xor(lmin, off));
        lmax = fmaxf(lmax, __shfl_xor(lmax, off));
    }
    __shared__ float smin[4], smax[4];
    if (l == 0) { smin[w] = lmin; smax[w] = lmax; }
    __syncthreads();
    if (threadIdx.x == 0) {
        float m0 = fminf(fminf(smin[0], smin[1]), fminf(smin[2], smin[3]));
        float m1 = fmaxf(fmaxf(smax[0], smax[1]), fmaxf(smax[2], smax[3]));
        atomicMin((int*)&mnb[c], __float_as_int(m0));
        atomicMax((int*)&mxb[c], __float_as_int(m1));
    }
}

// ---------------------------------------------------------------------------
// Kernel 3: main fused conv kernel.
// 8 outputs per thread: 32 lanes cover one 256-wide output row, a wave spans
// 2 consecutive rows. Window per row-pair = 2x7 quads (vs 2x6 for 4 outputs):
// LDS bytes/output x0.57. All FMA operands quad-aligned: s-quads built by
// scalar adds (no alignment constraint), then f32x4 fma -> v_pk_fma_f32 with
// no marshaling movs. LPITCH%32==20 puts the wave's two rows on
// complementary bank halves -> conflict-free ds_read_b128.
// asm "+v" pins keep loads as b128 (round-2 lesson).
// 180-deg point symmetry: w[ky][kx]==w[20-ky][20-kx] -> 1 add + 2 fma per pair.
// ---------------------------------------------------------------------------
__global__ __launch_bounds__(512, 4) void texsup_kernel(
    const float* __restrict__ x, const float* __restrict__ wtab,
    const unsigned* __restrict__ mnb, const unsigned* __restrict__ mxb,
    float* __restrict__ out)
{
    __shared__ float tile[LROWS][LPITCH];
    const int plane = blockIdx.z;          // 0..511
    const int b = plane >> 5, c = plane & 31;
    const float* __restrict__ img = x + (size_t)plane * (IMG_H*IMG_W);
    const int by0 = blockIdx.y * TY;
    const int tid = threadIdx.x;
    const int wid = tid >> 6, lane = tid & 63;
    const int ox4 = lane * 4;

    // stage: tile row r <-> img row by0 + r - 10; tile col t <-> img col t - 10
    for (int r = wid; r < LROWS; r += 8) {
        int gy = by0 + r - HALO;
        f32x4 vv = {0.f, 0.f, 0.f, 0.f};
        if ((unsigned)gy < IMG_H) vv = *(const f32x4*)(img + gy*IMG_W + ox4);
        *(f32x4*)&tile[r][HALO + ox4] = vv;
        if (lane < 10)       tile[r][lane]       = 0.f;    // cols 0..9
        else if (lane < 20)  tile[r][lane + 256] = 0.f;    // cols 266..275
    }
    __syncthreads();

    const float* __restrict__ wt = wtab + (size_t)(b & 7) * (441*2);
    const float mnv = __uint_as_float(mnb[c]);
    const float mxv = __uint_as_float(mxb[c]);
    const float inv = 1.0f / (mxv - mnv + 1e-8f);

    const int half = lane >> 5;           // which of the wave's 2 rows
    const int col0 = (lane & 31) * 8;     // tile col of first output

    #pragma unroll 1
    for (int p = 0; p < 2; ++p) {
        const int wy = (wid << 2) + (p << 1) + half;   // output row in tile, 0..31

        f32x4 aC0 = {0.f,0.f,0.f,0.f}, aC1 = {0.f,0.f,0.f,0.f};
        f32x4 aS0 = {0.f,0.f,0.f,0.f}, aS1 = {0.f,0.f,0.f,0.f};

        // symmetric row pairs (ky, 20-ky), ky = 0..9
        #pragma unroll 1
        for (int kyp = 0; kyp < 10; ++kyp) {
            const float* rA = &tile[wy + kyp][col0];
            const float* rB = &tile[wy + 20 - kyp][col0];
            f32x4 A[7], B[7];
            #pragma unroll
            for (int qd = 0; qd < 7; ++qd) {
                A[qd] = *(const f32x4*)(rA + 4*qd);
                B[qd] = *(const f32x4*)(rB + 4*qd);
            }
            #pragma unroll
            for (int qd = 0; qd < 7; ++qd) {
                asm volatile("" : "+v"(A[qd]));
                asm volatile("" : "+v"(B[qd]));
            }
            const float* w = wt + kyp*42;
            #pragma unroll
            for (int kx = 0; kx < 21; ++kx) {
                const float wcs = w[2*kx], wss = w[2*kx+1];
                f32x4 s0, s1;
                #pragma unroll
                for (int o = 0; o < 4; ++o) {
                    s0[o] = EL(A, kx+o)   + EL(B, 20-kx+o);
                    s1[o] = EL(A, kx+4+o) + EL(B, 24-kx+o);
                }
                f32x4 wcv = wcs, wsvv = wss;
                aC0 = __builtin_elementwise_fma(wcv,  s0, aC0);
                aC1 = __builtin_elementwise_fma(wcv,  s1, aC1);
                aS0 = __builtin_elementwise_fma(wsvv, s0, aS0);
                aS1 = __builtin_elementwise_fma(wsvv, s1, aS1);
            }
        }
        // middle row ky = 10
        {
            const float* rM = &tile[wy + 10][col0];
            f32x4 M[7];
            #pragma unroll
            for (int qd = 0; qd < 7; ++qd) M[qd] = *(const f32x4*)(rM + 4*qd);
            #pragma unroll
            for (int qd = 0; qd < 7; ++qd) asm volatile("" : "+v"(M[qd]));
            const float* w = wt + 210*2;
            #pragma unroll
            for (int kx = 0; kx < 10; ++kx) {
                const float wcs = w[2*kx], wss = w[2*kx+1];
                f32x4 s0, s1;
                #pragma unroll
                for (int o = 0; o < 4; ++o) {
                    s0[o] = EL(M, kx+o)   + EL(M, 20-kx+o);
                    s1[o] = EL(M, kx+4+o) + EL(M, 24-kx+o);
                }
                f32x4 wcv = wcs, wsvv = wss;
                aC0 = __builtin_elementwise_fma(wcv,  s0, aC0);
                aC1 = __builtin_elementwise_fma(wcv,  s1, aC1);
                aS0 = __builtin_elementwise_fma(wsvv, s0, aS0);
                aS1 = __builtin_elementwise_fma(wsvv, s1, aS1);
            }
            const float wcs = wt[220*2], wss = wt[220*2+1];
            f32x4 m0 = {EL(M,10), EL(M,11), EL(M,12), EL(M,13)};
            f32x4 m1 = {EL(M,14), EL(M,15), EL(M,16), EL(M,17)};
            f32x4 wcv = wcs, wsvv = wss;
            aC0 = __builtin_elementwise_fma(wcv,  m0, aC0);
            aC1 = __builtin_elementwise_fma(wcv,  m1, aC1);
            aS0 = __builtin_elementwise_fma(wsvv, m0, aS0);
            aS1 = __builtin_elementwise_fma(wsvv, m1, aS1);
        }

        // epilogue: local std from tile (zeros outside image == count_include_pad)
        // outputs o=0..7 -> window tile cols col0+9 .. col0+18 (10 values)
        float d1[10], d2[10];
        #pragma unroll
        for (int j = 0; j < 10; ++j) { d1[j] = 0.f; d2[j] = 0.f; }
        #pragma unroll
        for (int dy = -1; dy <= 1; ++dy) {
            const float* rw = &tile[wy + 10 + dy][col0 + 8];
            f32x4 u0 = *(const f32x4*)(rw);
            f32x4 u1 = *(const f32x4*)(rw + 4);
            f32x4 u2 = *(const f32x4*)(rw + 8);
            float vv[10] = {u0[1],u0[2],u0[3],u1[0],u1[1],u1[2],u1[3],u2[0],u2[1],u2[2]};
            #pragma unroll
            for (int j = 0; j < 10; ++j) { d1[j] += vv[j]; d2[j] += vv[j]*vv[j]; }
        }
        float res[8];
        #pragma unroll
        for (int o = 0; o < 8; ++o) {
            float t1 = d1[o] + d1[o+1] + d1[o+2];
            float t2 = d2[o] + d2[o+1] + d2[o+2];
            float avg = t1 * (1.0f/9.0f), avq = t2 * (1.0f/9.0f);
            float lv = sqrtf(fmaxf(avq - avg*avg, 1e-6f));
            lv = (lv - mnv) * inv;
            float cc = (o < 4) ? aC0[o] : aC1[o-4];
            float ss = (o < 4) ? aS0[o] : aS1[o-4];
            res[o] = fmaxf(cc - lv * ss, 0.0f);
        }
        float* op = out + (size_t)plane*(IMG_H*IMG_W) + (size_t)(by0+wy)*IMG_W + col0;
        *(f32x4*)(op)     = (f32x4){res[0], res[1], res[2], res[3]};
        *(f32x4*)(op + 4) = (f32x4){res[4], res[5], res[6], res[7]};
    }
}

// ---------------------------------------------------------------------------
extern "C" void kernel_launch(void* const* d_in, const int* in_sizes, int n_in,
                              void* d_out, int out_size, void* d_ws, size_t ws_size,
                              hipStream_t stream) {
    const float* x = (const float*)d_in[0];
    float* out = (float*)d_out;

    float*    wtab = (float*)d_ws;                                   // 8*441*2 f32 = 28224 B
    unsigned* mnb  = (unsigned*)((char*)d_ws + 8*441*2*sizeof(float));
    unsigned* mxb  = mnb + N_C;

    hipLaunchKernelGGL(prep_kernel, dim3(8), dim3(512), 0, stream, wtab, mnb, mxb);
    hipLaunchKernelGGL(lstd_minmax_kernel, dim3(4, N_B*N_C), dim3(256), 0, stream,
                       x, mnb, mxb);
    hipLaunchKernelGGL(texsup_kernel, dim3(1, IMG_H/TY, N_B*N_C), dim3(512), 0, stream,
                       x, wtab, mnb, mxb, out);
}